// Round 8
// baseline (284.050 us; speedup 1.0000x reference)
//
#include <hip/hip_runtime.h>
#include <hip/hip_bf16.h>

#define BETA_INV 12.5f
#define EXP2_SCALE 18.0336880111f   // 12.5 * log2(e)
#define EPS_NRM 1e-8f
#define NPAIR 4096
#define DDIM 256
#define MROWS 8192   // 2N
#define NTILE 64     // 8192 / 128
#define NBLK (NTILE * (NTILE + 1) / 2)   // 2080 upper-triangle tiles

typedef __attribute__((ext_vector_type(8))) short bf16x8;   // 8 bf16 = 4 VGPRs
typedef __attribute__((ext_vector_type(4))) float f32x4;

// ---------------------------------------------------------------------------
// Kernel 1: row-pair normalize (verified). One wave per pair.
// Also zeroes denom[] and the gram completion counter.
// ---------------------------------------------------------------------------
__global__ __launch_bounds__(256) void cl_normalize(
    const float* __restrict__ x1, const float* __restrict__ x2,
    ushort* __restrict__ zn, float* __restrict__ pos_half,
    float* __restrict__ denom, unsigned int* __restrict__ counter) {
  if (blockIdx.x < 32) denom[blockIdx.x * 256 + threadIdx.x] = 0.0f;
  if (blockIdx.x == 0 && threadIdx.x == 0) *counter = 0u;

  int wid  = threadIdx.x >> 6;
  int lane = threadIdx.x & 63;
  int row  = blockIdx.x * 4 + wid;           // pair index in [0, 4096)
  const float4* p1 = (const float4*)(x1 + row * DDIM);
  const float4* p2 = (const float4*)(x2 + row * DDIM);
  float4 a = p1[lane];
  float4 b = p2[lane];
  float s11 = a.x*a.x + a.y*a.y + a.z*a.z + a.w*a.w;
  float s22 = b.x*b.x + b.y*b.y + b.z*b.z + b.w*b.w;
  float s12 = a.x*b.x + a.y*b.y + a.z*b.z + a.w*b.w;
  #pragma unroll
  for (int m = 1; m < 64; m <<= 1) {
    s11 += __shfl_xor(s11, m);
    s22 += __shfl_xor(s22, m);
    s12 += __shfl_xor(s12, m);
  }
  float r1 = fmaxf(sqrtf(s11), EPS_NRM);
  float r2 = fmaxf(sqrtf(s22), EPS_NRM);
  float i1 = 1.0f / r1, i2 = 1.0f / r2;

  union { ushort4 u; __hip_bfloat16 h[4]; } w1, w2;
  w1.h[0] = __float2bfloat16(a.x * i1); w1.h[1] = __float2bfloat16(a.y * i1);
  w1.h[2] = __float2bfloat16(a.z * i1); w1.h[3] = __float2bfloat16(a.w * i1);
  w2.h[0] = __float2bfloat16(b.x * i2); w2.h[1] = __float2bfloat16(b.y * i2);
  w2.h[2] = __float2bfloat16(b.z * i2); w2.h[3] = __float2bfloat16(b.w * i2);
  *(ushort4*)(zn + row * DDIM + lane * 4)            = w1.u;
  *(ushort4*)(zn + (row + NPAIR) * DDIM + lane * 4)  = w2.u;

  if (lane == 0) pos_half[row] = s12 * i1 * i2 * BETA_INV;
}

// ---------------------------------------------------------------------------
// Kernel 2: symmetric Gram 128x128 tile + exp + row/col sums + fused finalize.
// Cost model from r2/r5/r6: per-CU throughput-bound on (ds_read 6.1K cy,
// exp/VALU epilogue ~5K cy). Fixes here:
//   - wave tile 64x64 (4 waves in 2x2): MFMA:ds_read = 4:1 (was 2:1); A from
//     global per chunk (r5-verified), only B through LDS.
//   - exp2 with folded scale (1 VALU op less per element)
//   - 16 KB LDS + launch_bounds(256,4): 4 blocks/CU for cross-block overlap
//   - last-done block computes the final loss (saves a dispatch)
// Staging/swizzle/schedule patterns identical to r5/r6 (zero-conflict,
// race-screened): per chunk {DMA B, load A, sync, compute, sync}.
// ---------------------------------------------------------------------------
__global__ __launch_bounds__(256, 4) void cl_gram_expsum(
    const ushort* __restrict__ zn, float* __restrict__ denom,
    const float* __restrict__ pos_half, unsigned int* __restrict__ counter,
    float* __restrict__ out) {
  // decode linear block id -> (i, j) with i <= j in the tile upper triangle
  int idx = blockIdx.x;
  int j = (int)((sqrtf(8.0f * idx + 1.0f) - 1.0f) * 0.5f);
  while ((j + 1) * (j + 2) / 2 <= idx) ++j;
  while (j * (j + 1) / 2 > idx) --j;
  int i = idx - j * (j + 1) / 2;
  int brow = i * 128;
  int bcol = j * 128;
  bool diag = (i == j);

  __shared__ ushort Bs[128][64];   // 16 KiB B chunk, swizzled rows

  int tid  = threadIdx.x;
  int wid  = tid >> 6;
  int lane = tid & 63;
  int l15  = lane & 15;
  int lg   = lane >> 4;
  int wr   = wid >> 1;       // 0..1: row half (64 rows)
  int wc   = wid & 1;        // 0..1: col half (64 cols)

  f32x4 acc[4][4];
  #pragma unroll
  for (int rt = 0; rt < 4; ++rt)
    #pragma unroll
    for (int ct = 0; ct < 4; ++ct)
      acc[rt][ct] = (f32x4){0.f, 0.f, 0.f, 0.f};

  int rlo  = lane >> 3;            // 0..7: row within 1KB DMA chunk
  int sswz = (lane & 7) ^ rlo;     // pre-swizzled source 16B-chunk index

  for (int kc = 0; kc < 4; ++kc) {
    // ---- stage B chunk kc: 4 x global_load_lds(16B) per wave, 8 rows each.
    // LDS(r, ch) holds global chunk ch ^ (r&7) (self-inverse; zero-conflict
    // geometry verified r2/r5/r6).
    #pragma unroll
    for (int it = 0; it < 4; ++it) {
      int r0 = wid * 32 + it * 8;
      const ushort* src =
          zn + (size_t)(bcol + r0 + rlo) * DDIM + kc * 64 + sswz * 8;
      __builtin_amdgcn_global_load_lds(
          (const __attribute__((address_space(1))) unsigned int*)src,
          (__attribute__((address_space(3))) unsigned int*)&Bs[r0][0],
          16, 0, 0);
    }

    // ---- A fragments for chunk kc (both ks): global -> regs, issued
    // before the sync so L2 latency overlaps the DMA drain (r5 pattern).
    bf16x8 af[2][4];
    #pragma unroll
    for (int ks = 0; ks < 2; ++ks)
      #pragma unroll
      for (int rt = 0; rt < 4; ++rt) {
        int r = brow + 64 * wr + 16 * rt + l15;
        af[ks][rt] = *(const bf16x8*)(zn + (size_t)r * DDIM + kc * 64 +
                                      ks * 32 + lg * 8);
      }

    __syncthreads();   // vmcnt(0) drain: B chunk resident, A frags in regs

    // ---- compute chunk: per thread 8 ds_read_b128 + 32 MFMA (4:1)
    #pragma unroll
    for (int ks = 0; ks < 2; ++ks) {
      bf16x8 bfv[4];
      #pragma unroll
      for (int ct = 0; ct < 4; ++ct) {
        int c  = 64 * wc + 16 * ct + l15;
        int su = (4 * ks + lg) ^ (l15 & 7);
        bfv[ct] = *(const bf16x8*)&Bs[c][su * 8];
      }
      #pragma unroll
      for (int rt = 0; rt < 4; ++rt)
        #pragma unroll
        for (int ct = 0; ct < 4; ++ct)
          acc[rt][ct] = __builtin_amdgcn_mfma_f32_16x16x32_bf16(
              af[ks][rt], bfv[ct], acc[rt][ct], 0, 0, 0);
    }

    __syncthreads();   // all waves done reading Bs before next stage
  }

  // ---- epilogue: e = exp2(sim * 18.034) (= exp(sim/beta)); on diagonal
  // tiles contribute iff gcol > grow (r3-verified rule). Each e feeds a
  // row sum (this wave's 64-col slice) and a col sum.
  float csum[4] = {0.f, 0.f, 0.f, 0.f};
  float* rowred = (float*)Bs;          // [2][128] floats
  float* colred = rowred + 256;        // [2][128] floats

  #pragma unroll
  for (int rt = 0; rt < 4; ++rt) {
    int lrow = 64 * wr + 16 * rt + lg * 4;     // row within tile
    #pragma unroll
    for (int reg = 0; reg < 4; ++reg) {
      float rs = 0.f;
      #pragma unroll
      for (int ct = 0; ct < 4; ++ct) {
        float e = __builtin_amdgcn_exp2f(acc[rt][ct][reg] * EXP2_SCALE);
        if (diag) {
          int grow = brow + lrow + reg;
          int gcol = bcol + 64 * wc + 16 * ct + l15;
          e = (gcol > grow) ? e : 0.f;
        }
        rs += e;
        csum[ct] += e;
      }
      rs += __shfl_xor(rs, 1);
      rs += __shfl_xor(rs, 2);
      rs += __shfl_xor(rs, 4);
      rs += __shfl_xor(rs, 8);
      if (l15 == 0) rowred[wc * 128 + lrow + reg] = rs;
    }
  }
  #pragma unroll
  for (int ct = 0; ct < 4; ++ct) {
    float c = csum[ct];
    c += __shfl_xor(c, 16);
    c += __shfl_xor(c, 32);
    if (lg == 0) colred[wr * 128 + 64 * wc + 16 * ct + l15] = c;
  }

  __syncthreads();

  if (tid < 128) {
    atomicAdd(&denom[brow + tid], rowred[tid] + rowred[128 + tid]);
  } else {
    int t = tid - 128;
    atomicAdd(&denom[bcol + t], colred[t] + colred[128 + t]);
  }

  // ---- fused finalize: last block to finish computes the loss
  __threadfence();
  __shared__ int isLast;
  if (tid == 0)
    isLast = (atomicAdd(counter, 1u) == (unsigned)(NBLK - 1)) ? 1 : 0;
  __syncthreads();
  if (isLast) {
    __threadfence();   // acquire: make all blocks' denom adds visible
    float s = 0.f, p = 0.f;
    for (int t = tid; t < MROWS; t += 256) {
      float d = __hip_atomic_load(&denom[t], __ATOMIC_RELAXED,
                                  __HIP_MEMORY_SCOPE_AGENT);
      s += __logf(d);
    }
    for (int t = tid; t < NPAIR; t += 256) p += pos_half[t];
    #pragma unroll
    for (int m = 1; m < 64; m <<= 1) {
      s += __shfl_xor(s, m);
      p += __shfl_xor(p, m);
    }
    if (lane == 0) { rowred[wid] = s; rowred[8 + wid] = p; }
    __syncthreads();
    if (tid == 0) {
      float S = rowred[0] + rowred[1] + rowred[2] + rowred[3];
      float P = rowred[8] + rowred[9] + rowred[10] + rowred[11];
      out[0] = (S - 2.f * P) / (float)MROWS;
    }
  }
}

extern "C" void kernel_launch(void* const* d_in, const int* in_sizes, int n_in,
                              void* d_out, int out_size, void* d_ws, size_t ws_size,
                              hipStream_t stream) {
  const float* x1 = (const float*)d_in[0];
  const float* x2 = (const float*)d_in[1];
  float* out = (float*)d_out;

  char* ws = (char*)d_ws;
  ushort* zn         = (ushort*)ws;                              // 4 MiB bf16
  float*  denom      = (float*)(ws + (size_t)MROWS * DDIM * 2);  // 32 KiB
  float*  posh       = (float*)(ws + (size_t)MROWS * DDIM * 2 + MROWS * 4);
  unsigned int* cnt  = (unsigned int*)(ws + (size_t)MROWS * DDIM * 2 +
                                       MROWS * 4 + NPAIR * 4);

  cl_normalize<<<NPAIR / 4, 256, 0, stream>>>(x1, x2, zn, posh, denom, cnt);
  cl_gram_expsum<<<NBLK, 256, 0, stream>>>(zn, denom, posh, cnt, out);
}

// Round 9
// 182.516 us; speedup vs baseline: 1.5563x; 1.5563x over previous
//
#include <hip/hip_runtime.h>
#include <hip/hip_bf16.h>

#define BETA_INV 12.5f
#define EXP2_SCALE 18.0336880111f   // 12.5 * log2(e)
#define EPS_NRM 1e-8f
#define NPAIR 4096
#define DDIM 256
#define MROWS 8192   // 2N
#define NTILE 64     // 8192 / 128
#define NBLK (NTILE * (NTILE + 1) / 2)   // 2080 upper-triangle tiles

typedef __attribute__((ext_vector_type(8))) short bf16x8;   // 8 bf16 = 4 VGPRs
typedef __attribute__((ext_vector_type(4))) float f32x4;

// ---------------------------------------------------------------------------
// Kernel 1: row-pair normalize (verified). One wave per pair.
// Also zeroes denom[] and the gram completion counter.
// ---------------------------------------------------------------------------
__global__ __launch_bounds__(256) void cl_normalize(
    const float* __restrict__ x1, const float* __restrict__ x2,
    ushort* __restrict__ zn, float* __restrict__ pos_half,
    float* __restrict__ denom, unsigned int* __restrict__ counter) {
  if (blockIdx.x < 32) denom[blockIdx.x * 256 + threadIdx.x] = 0.0f;
  if (blockIdx.x == 0 && threadIdx.x == 0) *counter = 0u;

  int wid  = threadIdx.x >> 6;
  int lane = threadIdx.x & 63;
  int row  = blockIdx.x * 4 + wid;           // pair index in [0, 4096)
  const float4* p1 = (const float4*)(x1 + row * DDIM);
  const float4* p2 = (const float4*)(x2 + row * DDIM);
  float4 a = p1[lane];
  float4 b = p2[lane];
  float s11 = a.x*a.x + a.y*a.y + a.z*a.z + a.w*a.w;
  float s22 = b.x*b.x + b.y*b.y + b.z*b.z + b.w*b.w;
  float s12 = a.x*b.x + a.y*b.y + a.z*b.z + a.w*b.w;
  #pragma unroll
  for (int m = 1; m < 64; m <<= 1) {
    s11 += __shfl_xor(s11, m);
    s22 += __shfl_xor(s22, m);
    s12 += __shfl_xor(s12, m);
  }
  float r1 = fmaxf(sqrtf(s11), EPS_NRM);
  float r2 = fmaxf(sqrtf(s22), EPS_NRM);
  float i1 = 1.0f / r1, i2 = 1.0f / r2;

  union { ushort4 u; __hip_bfloat16 h[4]; } w1, w2;
  w1.h[0] = __float2bfloat16(a.x * i1); w1.h[1] = __float2bfloat16(a.y * i1);
  w1.h[2] = __float2bfloat16(a.z * i1); w1.h[3] = __float2bfloat16(a.w * i1);
  w2.h[0] = __float2bfloat16(b.x * i2); w2.h[1] = __float2bfloat16(b.y * i2);
  w2.h[2] = __float2bfloat16(b.z * i2); w2.h[3] = __float2bfloat16(b.w * i2);
  *(ushort4*)(zn + row * DDIM + lane * 4)            = w1.u;
  *(ushort4*)(zn + (row + NPAIR) * DDIM + lane * 4)  = w2.u;

  if (lane == 0) pos_half[row] = s12 * i1 * i2 * BETA_INV;
}

// ---------------------------------------------------------------------------
// Kernel 2: symmetric Gram 128x128 tile + exp + row/col sums + fused finalize.
// r8 structure (64x64 wave tile -> MFMA:ds_read 4:1; exp2 epilogue; fused
// finalize) with the register cap FIXED: launch_bounds(256,2) gives a
// 256-reg/wave budget (need ~160: 64 AGPR acc + ~96 VGPR). r8's (256,4)
// capped at 128 -> spilled af[] to scratch -> 80 MB writes, 290 us.
// Staging/swizzle/schedule patterns identical to r5/r6 (zero-conflict):
// per chunk {DMA B, load A, sync, compute, sync}.
// ---------------------------------------------------------------------------
__global__ __launch_bounds__(256, 2) void cl_gram_expsum(
    const ushort* __restrict__ zn, float* __restrict__ denom,
    const float* __restrict__ pos_half, unsigned int* __restrict__ counter,
    float* __restrict__ out) {
  // decode linear block id -> (i, j) with i <= j in the tile upper triangle
  int idx = blockIdx.x;
  int j = (int)((sqrtf(8.0f * idx + 1.0f) - 1.0f) * 0.5f);
  while ((j + 1) * (j + 2) / 2 <= idx) ++j;
  while (j * (j + 1) / 2 > idx) --j;
  int i = idx - j * (j + 1) / 2;
  int brow = i * 128;
  int bcol = j * 128;
  bool diag = (i == j);

  __shared__ ushort Bs[128][64];   // 16 KiB B chunk, swizzled rows

  int tid  = threadIdx.x;
  int wid  = tid >> 6;
  int lane = tid & 63;
  int l15  = lane & 15;
  int lg   = lane >> 4;
  int wr   = wid >> 1;       // 0..1: row half (64 rows)
  int wc   = wid & 1;        // 0..1: col half (64 cols)

  f32x4 acc[4][4];
  #pragma unroll
  for (int rt = 0; rt < 4; ++rt)
    #pragma unroll
    for (int ct = 0; ct < 4; ++ct)
      acc[rt][ct] = (f32x4){0.f, 0.f, 0.f, 0.f};

  int rlo  = lane >> 3;            // 0..7: row within 1KB DMA chunk
  int sswz = (lane & 7) ^ rlo;     // pre-swizzled source 16B-chunk index

  for (int kc = 0; kc < 4; ++kc) {
    // ---- stage B chunk kc: 4 x global_load_lds(16B) per wave, 8 rows each.
    // LDS(r, ch) holds global chunk ch ^ (r&7) (self-inverse; zero-conflict
    // geometry verified r2/r5/r6).
    #pragma unroll
    for (int it = 0; it < 4; ++it) {
      int r0 = wid * 32 + it * 8;
      const ushort* src =
          zn + (size_t)(bcol + r0 + rlo) * DDIM + kc * 64 + sswz * 8;
      __builtin_amdgcn_global_load_lds(
          (const __attribute__((address_space(1))) unsigned int*)src,
          (__attribute__((address_space(3))) unsigned int*)&Bs[r0][0],
          16, 0, 0);
    }

    // ---- A fragments for chunk kc (both ks): global -> regs, issued
    // before the sync so L2 latency overlaps the DMA drain (r5 pattern).
    bf16x8 af[2][4];
    #pragma unroll
    for (int ks = 0; ks < 2; ++ks)
      #pragma unroll
      for (int rt = 0; rt < 4; ++rt) {
        int r = brow + 64 * wr + 16 * rt + l15;
        af[ks][rt] = *(const bf16x8*)(zn + (size_t)r * DDIM + kc * 64 +
                                      ks * 32 + lg * 8);
      }

    __syncthreads();   // vmcnt(0) drain: B chunk resident, A frags in regs

    // ---- compute chunk: per thread 8 ds_read_b128 + 32 MFMA (4:1)
    #pragma unroll
    for (int ks = 0; ks < 2; ++ks) {
      bf16x8 bfv[4];
      #pragma unroll
      for (int ct = 0; ct < 4; ++ct) {
        int c  = 64 * wc + 16 * ct + l15;
        int su = (4 * ks + lg) ^ (l15 & 7);
        bfv[ct] = *(const bf16x8*)&Bs[c][su * 8];
      }
      #pragma unroll
      for (int rt = 0; rt < 4; ++rt)
        #pragma unroll
        for (int ct = 0; ct < 4; ++ct)
          acc[rt][ct] = __builtin_amdgcn_mfma_f32_16x16x32_bf16(
              af[ks][rt], bfv[ct], acc[rt][ct], 0, 0, 0);
    }

    __syncthreads();   // all waves done reading Bs before next stage
  }

  // ---- epilogue: e = exp2(sim * 18.034) (= exp(sim/beta)); on diagonal
  // tiles contribute iff gcol > grow (r3-verified rule). Each e feeds a
  // row sum (this wave's 64-col slice) and a col sum.
  float csum[4] = {0.f, 0.f, 0.f, 0.f};
  float* rowred = (float*)Bs;          // [2][128] floats
  float* colred = rowred + 256;        // [2][128] floats

  #pragma unroll
  for (int rt = 0; rt < 4; ++rt) {
    int lrow = 64 * wr + 16 * rt + lg * 4;     // row within tile
    #pragma unroll
    for (int reg = 0; reg < 4; ++reg) {
      float rs = 0.f;
      #pragma unroll
      for (int ct = 0; ct < 4; ++ct) {
        float e = __builtin_amdgcn_exp2f(acc[rt][ct][reg] * EXP2_SCALE);
        if (diag) {
          int grow = brow + lrow + reg;
          int gcol = bcol + 64 * wc + 16 * ct + l15;
          e = (gcol > grow) ? e : 0.f;
        }
        rs += e;
        csum[ct] += e;
      }
      rs += __shfl_xor(rs, 1);
      rs += __shfl_xor(rs, 2);
      rs += __shfl_xor(rs, 4);
      rs += __shfl_xor(rs, 8);
      if (l15 == 0) rowred[wc * 128 + lrow + reg] = rs;
    }
  }
  #pragma unroll
  for (int ct = 0; ct < 4; ++ct) {
    float c = csum[ct];
    c += __shfl_xor(c, 16);
    c += __shfl_xor(c, 32);
    if (lg == 0) colred[wr * 128 + 64 * wc + 16 * ct + l15] = c;
  }

  __syncthreads();

  if (tid < 128) {
    atomicAdd(&denom[brow + tid], rowred[tid] + rowred[128 + tid]);
  } else {
    int t = tid - 128;
    atomicAdd(&denom[bcol + t], colred[t] + colred[128 + t]);
  }

  // ---- fused finalize: last block to finish computes the loss
  __threadfence();
  __shared__ int isLast;
  if (tid == 0)
    isLast = (atomicAdd(counter, 1u) == (unsigned)(NBLK - 1)) ? 1 : 0;
  __syncthreads();
  if (isLast) {
    __threadfence();   // acquire: make all blocks' denom adds visible
    float s = 0.f, p = 0.f;
    for (int t = tid; t < MROWS; t += 256) {
      float d = __hip_atomic_load(&denom[t], __ATOMIC_RELAXED,
                                  __HIP_MEMORY_SCOPE_AGENT);
      s += __logf(d);
    }
    for (int t = tid; t < NPAIR; t += 256) p += pos_half[t];
    #pragma unroll
    for (int m = 1; m < 64; m <<= 1) {
      s += __shfl_xor(s, m);
      p += __shfl_xor(p, m);
    }
    if (lane == 0) { rowred[wid] = s; rowred[8 + wid] = p; }
    __syncthreads();
    if (tid == 0) {
      float S = rowred[0] + rowred[1] + rowred[2] + rowred[3];
      float P = rowred[8] + rowred[9] + rowred[10] + rowred[11];
      out[0] = (S - 2.f * P) / (float)MROWS;
    }
  }
}

extern "C" void kernel_launch(void* const* d_in, const int* in_sizes, int n_in,
                              void* d_out, int out_size, void* d_ws, size_t ws_size,
                              hipStream_t stream) {
  const float* x1 = (const float*)d_in[0];
  const float* x2 = (const float*)d_in[1];
  float* out = (float*)d_out;

  char* ws = (char*)d_ws;
  ushort* zn         = (ushort*)ws;                              // 4 MiB bf16
  float*  denom      = (float*)(ws + (size_t)MROWS * DDIM * 2);  // 32 KiB
  float*  posh       = (float*)(ws + (size_t)MROWS * DDIM * 2 + MROWS * 4);
  unsigned int* cnt  = (unsigned int*)(ws + (size_t)MROWS * DDIM * 2 +
                                       MROWS * 4 + NPAIR * 4);

  cl_normalize<<<NPAIR / 4, 256, 0, stream>>>(x1, x2, zn, posh, denom, cnt);
  cl_gram_expsum<<<NBLK, 256, 0, stream>>>(zn, denom, posh, cnt, out);
}

// Round 10
// 61.992 us; speedup vs baseline: 4.5820x; 2.9442x over previous
//
#include <hip/hip_runtime.h>
#include <hip/hip_bf16.h>

#define BETA_INV 12.5f
#define EXP2_SCALE 18.0336880111f   // 12.5 * log2(e)
#define EPS_NRM 1e-8f
#define NPAIR 4096
#define DDIM 256
#define MROWS 8192   // 2N
#define NTILE 64     // 8192 / 128
#define NBLK (NTILE * (NTILE + 1) / 2)   // 2080 upper-triangle tiles

typedef __attribute__((ext_vector_type(8))) short bf16x8;   // 8 bf16 = 4 VGPRs
typedef __attribute__((ext_vector_type(4))) float f32x4;

// ---------------------------------------------------------------------------
// Kernel 1: row-pair normalize (verified). One wave per pair.
// Also zeroes denom[] so no separate memset dispatch.
// ---------------------------------------------------------------------------
__global__ __launch_bounds__(256) void cl_normalize(
    const float* __restrict__ x1, const float* __restrict__ x2,
    ushort* __restrict__ zn, float* __restrict__ pos_half,
    float* __restrict__ denom) {
  if (blockIdx.x < 32) denom[blockIdx.x * 256 + threadIdx.x] = 0.0f;

  int wid  = threadIdx.x >> 6;
  int lane = threadIdx.x & 63;
  int row  = blockIdx.x * 4 + wid;           // pair index in [0, 4096)
  const float4* p1 = (const float4*)(x1 + row * DDIM);
  const float4* p2 = (const float4*)(x2 + row * DDIM);
  float4 a = p1[lane];
  float4 b = p2[lane];
  float s11 = a.x*a.x + a.y*a.y + a.z*a.z + a.w*a.w;
  float s22 = b.x*b.x + b.y*b.y + b.z*b.z + b.w*b.w;
  float s12 = a.x*b.x + a.y*b.y + a.z*b.z + a.w*b.w;
  #pragma unroll
  for (int m = 1; m < 64; m <<= 1) {
    s11 += __shfl_xor(s11, m);
    s22 += __shfl_xor(s22, m);
    s12 += __shfl_xor(s12, m);
  }
  float r1 = fmaxf(sqrtf(s11), EPS_NRM);
  float r2 = fmaxf(sqrtf(s22), EPS_NRM);
  float i1 = 1.0f / r1, i2 = 1.0f / r2;

  union { ushort4 u; __hip_bfloat16 h[4]; } w1, w2;
  w1.h[0] = __float2bfloat16(a.x * i1); w1.h[1] = __float2bfloat16(a.y * i1);
  w1.h[2] = __float2bfloat16(a.z * i1); w1.h[3] = __float2bfloat16(a.w * i1);
  w2.h[0] = __float2bfloat16(b.x * i2); w2.h[1] = __float2bfloat16(b.y * i2);
  w2.h[2] = __float2bfloat16(b.z * i2); w2.h[3] = __float2bfloat16(b.w * i2);
  *(ushort4*)(zn + row * DDIM + lane * 4)            = w1.u;
  *(ushort4*)(zn + (row + NPAIR) * DDIM + lane * 4)  = w2.u;

  if (lane == 0) pos_half[row] = s12 * i1 * i2 * BETA_INV;
}

// ---------------------------------------------------------------------------
// Kernel 2: symmetric Gram 128x128 tile + exp + row/col sums.
// r9 structure (64x64 wave tile -> MFMA:ds_read 4:1; exp2 epilogue;
// launch_bounds(256,2) -> no spills) MINUS the fused finalize:
// r9's per-block __threadfence() (device-scope release = buffer_wbl2 L2
// writeback on CDNA) serialized the whole grid -> 4x slowdown at idle
// counters. Finalize is its own 2-us dispatch again.
// Staging/swizzle/schedule identical to r5/r6 (zero-conflict, verified):
// per chunk {DMA B, load A, sync, compute, sync}.
// ---------------------------------------------------------------------------
__global__ __launch_bounds__(256, 2) void cl_gram_expsum(
    const ushort* __restrict__ zn, float* __restrict__ denom) {
  // decode linear block id -> (i, j) with i <= j in the tile upper triangle
  int idx = blockIdx.x;
  int j = (int)((sqrtf(8.0f * idx + 1.0f) - 1.0f) * 0.5f);
  while ((j + 1) * (j + 2) / 2 <= idx) ++j;
  while (j * (j + 1) / 2 > idx) --j;
  int i = idx - j * (j + 1) / 2;
  int brow = i * 128;
  int bcol = j * 128;
  bool diag = (i == j);

  __shared__ ushort Bs[128][64];   // 16 KiB B chunk, swizzled rows

  int tid  = threadIdx.x;
  int wid  = tid >> 6;
  int lane = tid & 63;
  int l15  = lane & 15;
  int lg   = lane >> 4;
  int wr   = wid >> 1;       // 0..1: row half (64 rows)
  int wc   = wid & 1;        // 0..1: col half (64 cols)

  f32x4 acc[4][4];
  #pragma unroll
  for (int rt = 0; rt < 4; ++rt)
    #pragma unroll
    for (int ct = 0; ct < 4; ++ct)
      acc[rt][ct] = (f32x4){0.f, 0.f, 0.f, 0.f};

  int rlo  = lane >> 3;            // 0..7: row within 1KB DMA chunk
  int sswz = (lane & 7) ^ rlo;     // pre-swizzled source 16B-chunk index

  for (int kc = 0; kc < 4; ++kc) {
    // ---- stage B chunk kc: 4 x global_load_lds(16B) per wave, 8 rows each.
    // LDS(r, ch) holds global chunk ch ^ (r&7) (self-inverse; zero-conflict
    // geometry verified r2/r5/r6).
    #pragma unroll
    for (int it = 0; it < 4; ++it) {
      int r0 = wid * 32 + it * 8;
      const ushort* src =
          zn + (size_t)(bcol + r0 + rlo) * DDIM + kc * 64 + sswz * 8;
      __builtin_amdgcn_global_load_lds(
          (const __attribute__((address_space(1))) unsigned int*)src,
          (__attribute__((address_space(3))) unsigned int*)&Bs[r0][0],
          16, 0, 0);
    }

    // ---- A fragments for chunk kc (both ks): global -> regs, issued
    // before the sync so L2 latency overlaps the DMA drain (r5 pattern).
    bf16x8 af[2][4];
    #pragma unroll
    for (int ks = 0; ks < 2; ++ks)
      #pragma unroll
      for (int rt = 0; rt < 4; ++rt) {
        int r = brow + 64 * wr + 16 * rt + l15;
        af[ks][rt] = *(const bf16x8*)(zn + (size_t)r * DDIM + kc * 64 +
                                      ks * 32 + lg * 8);
      }

    __syncthreads();   // vmcnt(0) drain: B chunk resident, A frags in regs

    // ---- compute chunk: per thread 8 ds_read_b128 + 32 MFMA (4:1)
    #pragma unroll
    for (int ks = 0; ks < 2; ++ks) {
      bf16x8 bfv[4];
      #pragma unroll
      for (int ct = 0; ct < 4; ++ct) {
        int c  = 64 * wc + 16 * ct + l15;
        int su = (4 * ks + lg) ^ (l15 & 7);
        bfv[ct] = *(const bf16x8*)&Bs[c][su * 8];
      }
      #pragma unroll
      for (int rt = 0; rt < 4; ++rt)
        #pragma unroll
        for (int ct = 0; ct < 4; ++ct)
          acc[rt][ct] = __builtin_amdgcn_mfma_f32_16x16x32_bf16(
              af[ks][rt], bfv[ct], acc[rt][ct], 0, 0, 0);
    }

    __syncthreads();   // all waves done reading Bs before next stage
  }

  // ---- epilogue: e = exp2(sim * 18.034) (= exp(sim/beta)); on diagonal
  // tiles contribute iff gcol > grow (r3-verified rule). Each e feeds a
  // row sum (this wave's 64-col slice) and a col sum.
  float csum[4] = {0.f, 0.f, 0.f, 0.f};
  float* rowred = (float*)Bs;          // [2][128] floats
  float* colred = rowred + 256;        // [2][128] floats

  #pragma unroll
  for (int rt = 0; rt < 4; ++rt) {
    int lrow = 64 * wr + 16 * rt + lg * 4;     // row within tile
    #pragma unroll
    for (int reg = 0; reg < 4; ++reg) {
      float rs = 0.f;
      #pragma unroll
      for (int ct = 0; ct < 4; ++ct) {
        float e = __builtin_amdgcn_exp2f(acc[rt][ct][reg] * EXP2_SCALE);
        if (diag) {
          int grow = brow + lrow + reg;
          int gcol = bcol + 64 * wc + 16 * ct + l15;
          e = (gcol > grow) ? e : 0.f;
        }
        rs += e;
        csum[ct] += e;
      }
      rs += __shfl_xor(rs, 1);
      rs += __shfl_xor(rs, 2);
      rs += __shfl_xor(rs, 4);
      rs += __shfl_xor(rs, 8);
      if (l15 == 0) rowred[wc * 128 + lrow + reg] = rs;
    }
  }
  #pragma unroll
  for (int ct = 0; ct < 4; ++ct) {
    float c = csum[ct];
    c += __shfl_xor(c, 16);
    c += __shfl_xor(c, 32);
    if (lg == 0) colred[wr * 128 + 64 * wc + 16 * ct + l15] = c;
  }

  __syncthreads();

  if (tid < 128) {
    atomicAdd(&denom[brow + tid], rowred[tid] + rowred[128 + tid]);
  } else {
    int t = tid - 128;
    atomicAdd(&denom[bcol + t], colred[t] + colred[128 + t]);
  }
}

// ---------------------------------------------------------------------------
// Kernel 3: loss = (sum_i log(denom_i) - 2 * sum_i pos_half_i) / 8192
// ---------------------------------------------------------------------------
__global__ __launch_bounds__(1024) void cl_finalize(
    const float* __restrict__ denom, const float* __restrict__ pos_half,
    float* __restrict__ out) {
  float s = 0.f, p = 0.f;
  for (int i = threadIdx.x; i < MROWS; i += 1024) s += __logf(denom[i]);
  for (int i = threadIdx.x; i < NPAIR; i += 1024) p += pos_half[i];
  #pragma unroll
  for (int m = 1; m < 64; m <<= 1) {
    s += __shfl_xor(s, m);
    p += __shfl_xor(p, m);
  }
  __shared__ float red[2][16];
  int wid = threadIdx.x >> 6, lane = threadIdx.x & 63;
  if (lane == 0) { red[0][wid] = s; red[1][wid] = p; }
  __syncthreads();
  if (threadIdx.x == 0) {
    float S = 0.f, P = 0.f;
    #pragma unroll
    for (int w = 0; w < 16; ++w) { S += red[0][w]; P += red[1][w]; }
    out[0] = (S - 2.f * P) / (float)MROWS;
  }
}

extern "C" void kernel_launch(void* const* d_in, const int* in_sizes, int n_in,
                              void* d_out, int out_size, void* d_ws, size_t ws_size,
                              hipStream_t stream) {
  const float* x1 = (const float*)d_in[0];
  const float* x2 = (const float*)d_in[1];
  float* out = (float*)d_out;

  char* ws = (char*)d_ws;
  ushort* zn      = (ushort*)ws;                                 // 4 MiB bf16
  float*  denom   = (float*)(ws + (size_t)MROWS * DDIM * 2);     // 32 KiB
  float*  posh    = (float*)(ws + (size_t)MROWS * DDIM * 2 + MROWS * 4);

  cl_normalize<<<NPAIR / 4, 256, 0, stream>>>(x1, x2, zn, posh, denom);
  cl_gram_expsum<<<NBLK, 256, 0, stream>>>(zn, denom);
  cl_finalize<<<1, 1024, 0, stream>>>(denom, posh, out);
}